// Round 3
// baseline (316.713 us; speedup 1.0000x reference)
//
#include <hip/hip_runtime.h>
#include <hip/hip_bf16.h>
#include <math.h>

#define NP 512
#define NW 3584
#define NT 4096
#define FIN 256
#define H1 8
#define O1 32
#define H2 8
#define O2 256
#define NEG 0.2f

typedef __attribute__((ext_vector_type(8))) short bf16x8;
typedef __attribute__((ext_vector_type(4))) float f32x4;
typedef unsigned long long u64;

__device__ __forceinline__ unsigned short f2bf(float f) {
    unsigned u = __float_as_uint(f);
    unsigned r = (u + 0x7FFF + ((u >> 16) & 1)) >> 16;
    return (unsigned short)r;
}

__device__ __forceinline__ float fast_tanh(float x) {
    float ex = __expf(2.0f * x);
    return 1.0f - 2.0f / (ex + 1.0f);   // saturates to +-1 at inf/0
}

// ---- convert word_feature rows 0..3583 of hiddn_wp to bf16 ----
__global__ void k_conv_word(const float* __restrict__ wf, unsigned short* __restrict__ abf) {
    int i = blockIdx.x * 256 + threadIdx.x;
    if (i < NW * FIN) abf[i] = f2bf(wf[i]);
}

// ---- GAT1: h_prime1 [512][256] (col = h*32+o) + score dots ----
__global__ __launch_bounds__(256) void k_gat1_hp(
    const float* __restrict__ pf, const float* __restrict__ w1,
    const float* __restrict__ a_src1, const float* __restrict__ a_dst1,
    float* __restrict__ hp1, float* __restrict__ ss1, float* __restrict__ sd1)
{
    __shared__ float feat[8][FIN];
    int t = threadIdx.x;
    int n0 = blockIdx.x * 8;
    for (int q = 0; q < 8; q++) {
        int idx = q * 256 + t;
        feat[idx >> 8][idx & 255] = pf[(n0 + (idx >> 8)) * FIN + (idx & 255)];
    }
    __syncthreads();
    int h = t >> 5, o = t & 31;
    float acc[8] = {0,0,0,0,0,0,0,0};
    const float* wcol = w1 + h * FIN * O1 + o;
    for (int f = 0; f < FIN; f++) {
        float w = wcol[f * O1];
        #pragma unroll
        for (int i = 0; i < 8; i++) acc[i] += feat[i][f] * w;
    }
    float as = a_src1[h * O1 + o];
    float ad = a_dst1[h * O1 + o];
    #pragma unroll
    for (int i = 0; i < 8; i++) {
        hp1[(n0 + i) * 256 + t] = acc[i];
        float th = tanhf(acc[i]);
        float vs = th * as, vd = th * ad;
        #pragma unroll
        for (int off = 1; off < 32; off <<= 1) {
            vs += __shfl_xor(vs, off);
            vd += __shfl_xor(vd, off);
        }
        if (o == 0) { ss1[h * NP + n0 + i] = vs; sd1[h * NP + n0 + i] = vd; }
    }
}

// ---- GAT1 attention: 2 query rows per block (256 blocks) ----
__global__ __launch_bounds__(256) void k_gat1_attn(
    const int* __restrict__ adj, const float* __restrict__ hp1,
    const float* __restrict__ ss1, const float* __restrict__ sd1,
    const float* __restrict__ b1, unsigned short* __restrict__ abf)
{
    __shared__ float p[2][H1][NP];   // 32 KB
    __shared__ float den[2][H1];
    int t = threadIdx.x;
    int n0 = blockIdx.x * 2;
    for (int rr = 0; rr < 32; rr++) {
        int idx = rr * 256 + t;       // 8192 entries: i(1) h(3) m(9)
        int i = idx >> 12, h = (idx >> 9) & 7, m = idx & 511;
        float a = adj[(n0 + i) * NP + m] > 0 ? 1.0f : 0.0f;
        float e = ss1[h * NP + n0 + i] + sd1[h * NP + m];
        e = fmaxf(e, NEG * e);
        p[i][h][m] = a * __expf(e);
    }
    __syncthreads();
    int w = t >> 6, l = t & 63;
    {
        int i = w & 1;
        #pragma unroll
        for (int hh = 0; hh < 4; hh++) {
            int h = (w >> 1) * 4 + hh;
            float s = 0;
            #pragma unroll
            for (int q = 0; q < 8; q++) s += p[i][h][l + 64 * q];
            #pragma unroll
            for (int off = 1; off < 64; off <<= 1) s += __shfl_xor(s, off);
            if (l == 0) den[i][h] = s;
        }
    }
    __syncthreads();
    int h = t >> 5, o = t & 31;
    float acc[2] = {0, 0};
    #pragma unroll 4
    for (int m = 0; m < NP; m++) {
        float v = hp1[m * 256 + t];
        acc[0] += p[0][h][m] * v;
        acc[1] += p[1][h][m] * v;
    }
    float bo = b1[o];
    #pragma unroll
    for (int i = 0; i < 2; i++) {
        float r = acc[i] / den[i][h] + bo;
        r = r > 0.f ? r : expm1f(r);   // elu
        abf[(NW + n0 + i) * FIN + t] = f2bf(r);
    }
}

// ---- transpose+convert w2 [h][f][o] -> bf16 Bt [h][o][f] ----
__global__ void k_conv_w2(const float* __restrict__ w2, unsigned short* __restrict__ btbf) {
    int idx = blockIdx.x * 256 + threadIdx.x;
    int f = idx & 255, o = (idx >> 8) & 255, h = idx >> 16;
    btbf[idx] = f2bf(w2[(h * FIN + f) * O2 + o]);
}

// ---- pack wp_adj rows 0..3583 into bitmasks (dwordx4 + shuffle-OR) ----
__global__ __launch_bounds__(256) void k_pack_adj(const int* __restrict__ adj,
                                                  u64* __restrict__ packed) {
    int w = threadIdx.x >> 6, l = threadIdx.x & 63;
    int r = blockIdx.x * 4 + w;
    const int4* row = (const int4*)(adj + (size_t)r * NT);
    for (int c4 = 0; c4 < 16; c4++) {
        int4 x = row[c4 * 64 + l];
        u64 nib = (u64)((x.x != 0 ? 1 : 0) | (x.y != 0 ? 2 : 0) |
                        (x.z != 0 ? 4 : 0) | (x.w != 0 ? 8 : 0));
        u64 v = nib << (4 * (l & 15));
        v |= __shfl_xor(v, 1);
        v |= __shfl_xor(v, 2);
        v |= __shfl_xor(v, 4);
        v |= __shfl_xor(v, 8);
        if ((l & 15) == 0) packed[(size_t)r * 64 + c4 * 4 + (l >> 4)] = v;
    }
}

// ---- hp2 GEMM with FUSED ss2/sd2/G reduction epilogue ----
__global__ __launch_bounds__(256) void k_gemm_hp2(
    const unsigned short* __restrict__ abf, const unsigned short* __restrict__ btbf,
    const float* __restrict__ a_src2, const float* __restrict__ a_dst2,
    const float* __restrict__ W_fc, float* __restrict__ gpart)
{
    int bid = blockIdx.x;
    int h = bid >> 6;
    int rem = bid & 63;
    int mt = rem >> 1, nt = rem & 1;
    int w = threadIdx.x >> 6, l = threadIdx.x & 63;
    int m0 = mt * 128 + (w >> 1) * 64;
    int n0 = nt * 128 + (w & 1) * 64;
    int lr = l & 15, lq = l >> 4;
    const unsigned short* bbase = btbf + h * O2 * FIN;
    f32x4 acc[4][4];
    #pragma unroll
    for (int i = 0; i < 4; i++)
        #pragma unroll
        for (int j = 0; j < 4; j++) acc[i][j] = (f32x4){0.f, 0.f, 0.f, 0.f};
    for (int k = 0; k < FIN; k += 32) {
        bf16x8 a[4], b[4];
        int kc = k + lq * 8;
        #pragma unroll
        for (int i = 0; i < 4; i++)
            a[i] = *(const bf16x8*)(abf + (m0 + i * 16 + lr) * FIN + kc);
        #pragma unroll
        for (int j = 0; j < 4; j++)
            b[j] = *(const bf16x8*)(bbase + (n0 + j * 16 + lr) * FIN + kc);
        #pragma unroll
        for (int i = 0; i < 4; i++)
            #pragma unroll
            for (int j = 0; j < 4; j++)
                acc[i][j] = __builtin_amdgcn_mfma_f32_16x16x32_bf16(a[i], b[j], acc[i][j], 0, 0, 0);
    }
    int slice = nt * 2 + (w & 1);
    float as[4], ad[4], wfc[4][5];
    #pragma unroll
    for (int j = 0; j < 4; j++) {
        int col = n0 + j * 16 + lr;
        as[j] = a_src2[h * O2 + col];
        ad[j] = a_dst2[h * O2 + col];
        #pragma unroll
        for (int jj = 0; jj < 5; jj++) wfc[j][jj] = W_fc[col * 5 + jj];
    }
    float* base = gpart + ((size_t)h * 4 + slice) * NT * 8;
    #pragma unroll
    for (int i = 0; i < 4; i++) {
        #pragma unroll
        for (int r = 0; r < 4; r++) {
            float s[7] = {0,0,0,0,0,0,0};
            #pragma unroll
            for (int j = 0; j < 4; j++) {
                float x = acc[i][j][r];
                float th = fast_tanh(x);
                s[0] += th * as[j];
                s[1] += th * ad[j];
                #pragma unroll
                for (int jj = 0; jj < 5; jj++) s[2 + jj] += x * wfc[j][jj];
            }
            #pragma unroll
            for (int off = 1; off < 16; off <<= 1)
                #pragma unroll
                for (int q = 0; q < 7; q++) s[q] += __shfl_xor(s[q], off);
            if (lr == 0) {
                int m = m0 + i * 16 + lq * 4 + r;
                float* dst = base + (size_t)m * 8;
                #pragma unroll
                for (int q = 0; q < 7; q++) dst[q] = s[q];
            }
        }
    }
}

// ---- combine slices -> negss / E / Ep tables + interleaved T {sd,F,Fp,g0..g4} ----
__global__ __launch_bounds__(256) void k_comb_hp2(
    const float* __restrict__ gpart,
    float* __restrict__ negss, float* __restrict__ Etab, float* __restrict__ Eptab,
    float* __restrict__ T)
{
    int idx = blockIdx.x * 256 + threadIdx.x;   // h*NT + m
    int h = idx >> 12, m = idx & (NT - 1);
    float s[7] = {0,0,0,0,0,0,0};
    #pragma unroll
    for (int sl = 0; sl < 4; sl++) {
        const float* p = gpart + (((size_t)h * 4 + sl) * NT + m) * 8;
        #pragma unroll
        for (int q = 0; q < 7; q++) s[q] += p[q];
    }
    negss[idx] = -s[0];
    Etab[idx]  = __expf(s[0]);
    Eptab[idx] = __expf(NEG * s[0]);
    float4 t0 = {s[1], __expf(s[1]), __expf(NEG * s[1]), s[2]};
    float4 t1 = {s[3], s[4], s[5], s[6]};
    *(float4*)(T + (size_t)idx * 8)     = t0;
    *(float4*)(T + (size_t)idx * 8 + 4) = t1;
}

// ---- c[j] = b2 . W_fc[:,j] ----
__global__ void k_cvec(const float* __restrict__ b2, const float* __restrict__ W_fc,
                       float* __restrict__ c) {
    int t = threadIdx.x;
    float v[5];
    #pragma unroll
    for (int j = 0; j < 5; j++) v[j] = b2[t] * W_fc[t * 5 + j];
    #pragma unroll
    for (int off = 1; off < 64; off <<= 1)
        #pragma unroll
        for (int j = 0; j < 5; j++) v[j] += __shfl_xor(v[j], off);
    __shared__ float red[4][5];
    int w = t >> 6, l = t & 63;
    if (l == 0) { for (int j = 0; j < 5; j++) red[w][j] = v[j]; }
    __syncthreads();
    if (t == 0)
        for (int j = 0; j < 5; j++) c[j] = red[0][j] + red[1][j] + red[2][j] + red[3][j];
}

// ---- GAT2 attention: exp-free inner loop, sgpr-mask adjacency ----
// block = 256 thr (4 head-waves), 16 query rows, 1024-m chunk
// grid: nb(224) x c(4) x hg(2) ; part[((c*3584+n)*8+h)*6 + {den,num0..4}]
__global__ __launch_bounds__(256) void k_gat2_attn(
    const u64* __restrict__ packed, const float* __restrict__ negss,
    const float* __restrict__ Etab, const float* __restrict__ Eptab,
    const float* __restrict__ T, float* __restrict__ part)
{
    int t = threadIdx.x;
    int l = t & 63;
    int b = blockIdx.x;
    int hg = b & 1, c = (b >> 1) & 3, nb = b >> 3;
    int h = hg * 4 + (t >> 6);
    int n0 = nb * 16;
    float ns[16], E[16], Ep[16];
    #pragma unroll
    for (int i = 0; i < 16; i++) {
        ns[i] = negss[h * NT + n0 + i];
        E[i]  = Etab[h * NT + n0 + i];
        Ep[i] = Eptab[h * NT + n0 + i];
    }
    float den[16];
    float num[16][5];
    #pragma unroll
    for (int i = 0; i < 16; i++) {
        den[i] = 0.f;
        #pragma unroll
        for (int j = 0; j < 5; j++) num[i][j] = 0.f;
    }
    const float* Th = T + (size_t)h * NT * 8;
    const u64* prow = packed + c * 16;
    for (int q = 0; q < 16; q++) {
        int m = c * 1024 + q * 64 + l;
        const float* tp = Th + (size_t)m * 8;
        float4 t0 = *(const float4*)tp;
        float4 t1 = *(const float4*)(tp + 4);
        float sd = t0.x, F = t0.y, Fp = t0.z;
        float g0 = t0.w, g1 = t1.x, g2 = t1.y, g3 = t1.z, g4 = t1.w;
        #pragma unroll
        for (int i = 0; i < 16; i++) {
            u64 word = prow[(size_t)(n0 + i) * 64 + q];   // workgroup-uniform -> s_load
            bool sel = sd >= ns[i];
            float f = sel ? F : Fp;
            float e = sel ? E[i] : Ep[i];
            float pp0 = f * e;
            float pp;
            asm("v_cndmask_b32 %0, 0, %1, %2" : "=v"(pp) : "v"(pp0), "s"(word));
            den[i] += pp;
            num[i][0] = fmaf(pp, g0, num[i][0]);
            num[i][1] = fmaf(pp, g1, num[i][1]);
            num[i][2] = fmaf(pp, g2, num[i][2]);
            num[i][3] = fmaf(pp, g3, num[i][3]);
            num[i][4] = fmaf(pp, g4, num[i][4]);
        }
    }
    #pragma unroll
    for (int i = 0; i < 16; i++) {
        float v[6];
        v[0] = den[i];
        #pragma unroll
        for (int j = 0; j < 5; j++) v[1 + j] = num[i][j];
        #pragma unroll
        for (int off = 1; off < 64; off <<= 1)
            #pragma unroll
            for (int k = 0; k < 6; k++) v[k] += __shfl_xor(v[k], off);
        if (l == 0) {
            float* dst = part + (((size_t)c * NW + n0 + i) * 8 + h) * 6;
            #pragma unroll
            for (int k = 0; k < 6; k++) dst[k] = v[k];
        }
    }
}

// ---- combine chunks + heads -> hf[n][5] ----
__global__ __launch_bounds__(256) void k_gat2_comb(const float* __restrict__ part,
                                                   float* __restrict__ hf) {
    int idx = blockIdx.x * 256 + threadIdx.x;  // n*8 + h
    int n = idx >> 3, h = idx & 7;
    float den = 0, num[5] = {0,0,0,0,0};
    #pragma unroll
    for (int cc = 0; cc < 4; cc++) {
        const float* p = part + (((size_t)cc * NW + n) * 8 + h) * 6;
        den += p[0];
        #pragma unroll
        for (int j = 0; j < 5; j++) num[j] += p[1 + j];
    }
    float inv = 1.0f / (den * 8.0f);
    float v[5];
    #pragma unroll
    for (int j = 0; j < 5; j++) v[j] = num[j] * inv;
    #pragma unroll
    for (int off = 1; off < 8; off <<= 1)
        #pragma unroll
        for (int j = 0; j < 5; j++) v[j] += __shfl_xor(v[j], off);
    if (h == 0) {
        #pragma unroll
        for (int j = 0; j < 5; j++) hf[n * 5 + j] = v[j];
    }
}

// ---- out[b][j] = (input[b].hf[:,j]) / sum(input[b]) + c[j] + b_fc[j] ----
__global__ __launch_bounds__(256) void k_final(
    const float* __restrict__ input, const float* __restrict__ hf,
    const float* __restrict__ cvec, const float* __restrict__ b_fc,
    float* __restrict__ out)
{
    int b = blockIdx.x, t = threadIdx.x;
    const float4* row4 = (const float4*)(input + (size_t)b * NW);
    const float4* hf4 = (const float4*)hf;
    float s = 0.f, a[5] = {0.f, 0.f, 0.f, 0.f, 0.f};
    for (int idx = t; idx < NW / 4; idx += 256) {
        float4 x = row4[idx];
        float f[20];
        #pragma unroll
        for (int q = 0; q < 5; q++) *(float4*)(f + 4 * q) = hf4[idx * 5 + q];
        s += x.x + x.y + x.z + x.w;
        #pragma unroll
        for (int j = 0; j < 5; j++)
            a[j] += x.x * f[j] + x.y * f[5 + j] + x.z * f[10 + j] + x.w * f[15 + j];
    }
    #pragma unroll
    for (int off = 1; off < 64; off <<= 1) {
        s += __shfl_xor(s, off);
        #pragma unroll
        for (int j = 0; j < 5; j++) a[j] += __shfl_xor(a[j], off);
    }
    __shared__ float red[4][6];
    int w = t >> 6, l = t & 63;
    if (l == 0) { red[w][0] = s; for (int j = 0; j < 5; j++) red[w][j + 1] = a[j]; }
    __syncthreads();
    if (t < 5) {
        float st = red[0][0] + red[1][0] + red[2][0] + red[3][0];
        float aj = red[0][t + 1] + red[1][t + 1] + red[2][t + 1] + red[3][t + 1];
        out[b * 5 + t] = aj / st + cvec[t] + b_fc[t];
    }
}

extern "C" void kernel_launch(void* const* d_in, const int* in_sizes, int n_in,
                              void* d_out, int out_size, void* d_ws, size_t ws_size,
                              hipStream_t stream) {
    const float* input   = (const float*)d_in[0];
    const float* pf      = (const float*)d_in[1];
    const float* wf      = (const float*)d_in[2];
    const float* w1      = (const float*)d_in[3];
    const float* a_src1  = (const float*)d_in[4];
    const float* a_dst1  = (const float*)d_in[5];
    const float* b1      = (const float*)d_in[6];
    const float* w2      = (const float*)d_in[7];
    const float* a_src2  = (const float*)d_in[8];
    const float* a_dst2  = (const float*)d_in[9];
    const float* b2      = (const float*)d_in[10];
    const float* W_fc    = (const float*)d_in[11];
    const float* b_fc    = (const float*)d_in[12];
    const int* pern_adj  = (const int*)d_in[13];
    const int* wp_adj    = (const int*)d_in[14];
    float* out = (float*)d_out;

    char* ws = (char*)d_ws;
    unsigned short* abf    = (unsigned short*)(ws);            // 2 MB
    unsigned short* btbf   = (unsigned short*)(ws + 2097152);  // 1 MB
    float*          hp1    = (float*)(ws + 3145728);           // 512 KB
    float*          ss1    = (float*)(ws + 3670016);           // 16 KB
    float*          sd1    = (float*)(ws + 3686400);           // 16 KB
    float*          negss  = (float*)(ws + 3702784);           // 128 KB
    float*          Etab   = (float*)(ws + 3833856);           // 128 KB
    float*          Eptab  = (float*)(ws + 3964928);           // 128 KB
    float*          T      = (float*)(ws + 4096000);           // 1 MB
    float*          hf     = (float*)(ws + 5144576);           // 70 KB
    float*          cvec   = (float*)(ws + 5216256);           // 64 B
    u64*            packed = (u64*)(ws + 5216512);             // 1.75 MB
    float*          gpart  = (float*)(ws + 7051520);           // 4 MB
    float*          part   = (float*)(ws + 11245824);          // 2.625 MB

    k_conv_word<<<3584, 256, 0, stream>>>(wf, abf);
    k_gat1_hp<<<64, 256, 0, stream>>>(pf, w1, a_src1, a_dst1, hp1, ss1, sd1);
    k_gat1_attn<<<256, 256, 0, stream>>>(pern_adj, hp1, ss1, sd1, b1, abf);
    k_conv_w2<<<2048, 256, 0, stream>>>(w2, btbf);
    k_pack_adj<<<896, 256, 0, stream>>>(wp_adj, packed);
    k_gemm_hp2<<<512, 256, 0, stream>>>(abf, btbf, a_src2, a_dst2, W_fc, gpart);
    k_comb_hp2<<<128, 256, 0, stream>>>(gpart, negss, Etab, Eptab, T);
    k_cvec<<<1, 256, 0, stream>>>(b2, W_fc, cvec);
    k_gat2_attn<<<1792, 256, 0, stream>>>(packed, negss, Etab, Eptab, T, part);
    k_gat2_comb<<<112, 256, 0, stream>>>(part, hf);
    k_final<<<1024, 256, 0, stream>>>(input, hf, cvec, b_fc, out);
}

// Round 4
// 297.430 us; speedup vs baseline: 1.0648x; 1.0648x over previous
//
#include <hip/hip_runtime.h>
#include <hip/hip_bf16.h>
#include <math.h>

#define NP 512
#define NW 3584
#define NT 4096
#define FIN 256
#define H1 8
#define O1 32
#define H2 8
#define O2 256
#define NEG 0.2f

typedef __attribute__((ext_vector_type(8))) short bf16x8;
typedef __attribute__((ext_vector_type(4))) float f32x4;
typedef unsigned long long u64;

__device__ __forceinline__ unsigned short f2bf(float f) {
    unsigned u = __float_as_uint(f);
    unsigned r = (u + 0x7FFF + ((u >> 16) & 1)) >> 16;
    return (unsigned short)r;
}

__device__ __forceinline__ float fast_tanh(float x) {
    float ex = __expf(2.0f * x);
    return 1.0f - 2.0f / (ex + 1.0f);   // saturates to +-1 at inf/0
}

__device__ __forceinline__ float rfl(float x) {
    return __uint_as_float(__builtin_amdgcn_readfirstlane(__float_as_uint(x)));
}

// ---- convert word_feature rows 0..3583 of hiddn_wp to bf16 ----
__global__ void k_conv_word(const float* __restrict__ wf, unsigned short* __restrict__ abf) {
    int i = blockIdx.x * 256 + threadIdx.x;
    if (i < NW * FIN) abf[i] = f2bf(wf[i]);
}

// ---- GAT1: h_prime1 [512][256] (col = h*32+o) + score dots ----
__global__ __launch_bounds__(256) void k_gat1_hp(
    const float* __restrict__ pf, const float* __restrict__ w1,
    const float* __restrict__ a_src1, const float* __restrict__ a_dst1,
    float* __restrict__ hp1, float* __restrict__ ss1, float* __restrict__ sd1)
{
    __shared__ float feat[8][FIN];
    int t = threadIdx.x;
    int n0 = blockIdx.x * 8;
    for (int q = 0; q < 8; q++) {
        int idx = q * 256 + t;
        feat[idx >> 8][idx & 255] = pf[(n0 + (idx >> 8)) * FIN + (idx & 255)];
    }
    __syncthreads();
    int h = t >> 5, o = t & 31;
    float acc[8] = {0,0,0,0,0,0,0,0};
    const float* wcol = w1 + h * FIN * O1 + o;
    for (int f = 0; f < FIN; f++) {
        float w = wcol[f * O1];
        #pragma unroll
        for (int i = 0; i < 8; i++) acc[i] += feat[i][f] * w;
    }
    float as = a_src1[h * O1 + o];
    float ad = a_dst1[h * O1 + o];
    #pragma unroll
    for (int i = 0; i < 8; i++) {
        hp1[(n0 + i) * 256 + t] = acc[i];
        float th = tanhf(acc[i]);
        float vs = th * as, vd = th * ad;
        #pragma unroll
        for (int off = 1; off < 32; off <<= 1) {
            vs += __shfl_xor(vs, off);
            vd += __shfl_xor(vd, off);
        }
        if (o == 0) { ss1[h * NP + n0 + i] = vs; sd1[h * NP + n0 + i] = vd; }
    }
}

// ---- GAT1 attention: 2 query rows per block (256 blocks) ----
__global__ __launch_bounds__(256) void k_gat1_attn(
    const int* __restrict__ adj, const float* __restrict__ hp1,
    const float* __restrict__ ss1, const float* __restrict__ sd1,
    const float* __restrict__ b1, unsigned short* __restrict__ abf)
{
    __shared__ float p[2][H1][NP];   // 32 KB
    __shared__ float den[2][H1];
    int t = threadIdx.x;
    int n0 = blockIdx.x * 2;
    for (int rr = 0; rr < 32; rr++) {
        int idx = rr * 256 + t;       // 8192 entries: i(1) h(3) m(9)
        int i = idx >> 12, h = (idx >> 9) & 7, m = idx & 511;
        float a = adj[(n0 + i) * NP + m] > 0 ? 1.0f : 0.0f;
        float e = ss1[h * NP + n0 + i] + sd1[h * NP + m];
        e = fmaxf(e, NEG * e);
        p[i][h][m] = a * __expf(e);
    }
    __syncthreads();
    int w = t >> 6, l = t & 63;
    {
        int i = w & 1;
        #pragma unroll
        for (int hh = 0; hh < 4; hh++) {
            int h = (w >> 1) * 4 + hh;
            float s = 0;
            #pragma unroll
            for (int q = 0; q < 8; q++) s += p[i][h][l + 64 * q];
            #pragma unroll
            for (int off = 1; off < 64; off <<= 1) s += __shfl_xor(s, off);
            if (l == 0) den[i][h] = s;
        }
    }
    __syncthreads();
    int h = t >> 5, o = t & 31;
    float acc[2] = {0, 0};
    #pragma unroll 4
    for (int m = 0; m < NP; m++) {
        float v = hp1[m * 256 + t];
        acc[0] += p[0][h][m] * v;
        acc[1] += p[1][h][m] * v;
    }
    float bo = b1[o];
    #pragma unroll
    for (int i = 0; i < 2; i++) {
        float r = acc[i] / den[i][h] + bo;
        r = r > 0.f ? r : expm1f(r);   // elu
        abf[(NW + n0 + i) * FIN + t] = f2bf(r);
    }
}

// ---- transpose+convert w2 [h][f][o] -> bf16 Bt [h][o][f] ----
__global__ void k_conv_w2(const float* __restrict__ w2, unsigned short* __restrict__ btbf) {
    int idx = blockIdx.x * 256 + threadIdx.x;
    int f = idx & 255, o = (idx >> 8) & 255, h = idx >> 16;
    btbf[idx] = f2bf(w2[(h * FIN + f) * O2 + o]);
}

// ---- pack wp_adj rows 0..3583 into bitmasks (dwordx4 + shuffle-OR) ----
__global__ __launch_bounds__(256) void k_pack_adj(const int* __restrict__ adj,
                                                  u64* __restrict__ packed) {
    int w = threadIdx.x >> 6, l = threadIdx.x & 63;
    int r = blockIdx.x * 4 + w;
    const int4* row = (const int4*)(adj + (size_t)r * NT);
    for (int c4 = 0; c4 < 16; c4++) {
        int4 x = row[c4 * 64 + l];
        u64 nib = (u64)((x.x != 0 ? 1 : 0) | (x.y != 0 ? 2 : 0) |
                        (x.z != 0 ? 4 : 0) | (x.w != 0 ? 8 : 0));
        u64 v = nib << (4 * (l & 15));
        v |= __shfl_xor(v, 1);
        v |= __shfl_xor(v, 2);
        v |= __shfl_xor(v, 4);
        v |= __shfl_xor(v, 8);
        if ((l & 15) == 0) packed[(size_t)r * 64 + c4 * 4 + (l >> 4)] = v;
    }
}

// ---- hp2 GEMM with FUSED ss2/sd2/G reduction epilogue ----
__global__ __launch_bounds__(256) void k_gemm_hp2(
    const unsigned short* __restrict__ abf, const unsigned short* __restrict__ btbf,
    const float* __restrict__ a_src2, const float* __restrict__ a_dst2,
    const float* __restrict__ W_fc, float* __restrict__ gpart)
{
    int bid = blockIdx.x;
    int h = bid >> 6;
    int rem = bid & 63;
    int mt = rem >> 1, nt = rem & 1;
    int w = threadIdx.x >> 6, l = threadIdx.x & 63;
    int m0 = mt * 128 + (w >> 1) * 64;
    int n0 = nt * 128 + (w & 1) * 64;
    int lr = l & 15, lq = l >> 4;
    const unsigned short* bbase = btbf + h * O2 * FIN;
    f32x4 acc[4][4];
    #pragma unroll
    for (int i = 0; i < 4; i++)
        #pragma unroll
        for (int j = 0; j < 4; j++) acc[i][j] = (f32x4){0.f, 0.f, 0.f, 0.f};
    for (int k = 0; k < FIN; k += 32) {
        bf16x8 a[4], b[4];
        int kc = k + lq * 8;
        #pragma unroll
        for (int i = 0; i < 4; i++)
            a[i] = *(const bf16x8*)(abf + (m0 + i * 16 + lr) * FIN + kc);
        #pragma unroll
        for (int j = 0; j < 4; j++)
            b[j] = *(const bf16x8*)(bbase + (n0 + j * 16 + lr) * FIN + kc);
        #pragma unroll
        for (int i = 0; i < 4; i++)
            #pragma unroll
            for (int j = 0; j < 4; j++)
                acc[i][j] = __builtin_amdgcn_mfma_f32_16x16x32_bf16(a[i], b[j], acc[i][j], 0, 0, 0);
    }
    int slice = nt * 2 + (w & 1);
    float as[4], ad[4], wfc[4][5];
    #pragma unroll
    for (int j = 0; j < 4; j++) {
        int col = n0 + j * 16 + lr;
        as[j] = a_src2[h * O2 + col];
        ad[j] = a_dst2[h * O2 + col];
        #pragma unroll
        for (int jj = 0; jj < 5; jj++) wfc[j][jj] = W_fc[col * 5 + jj];
    }
    float* base = gpart + ((size_t)h * 4 + slice) * NT * 8;
    #pragma unroll
    for (int i = 0; i < 4; i++) {
        #pragma unroll
        for (int r = 0; r < 4; r++) {
            float s[7] = {0,0,0,0,0,0,0};
            #pragma unroll
            for (int j = 0; j < 4; j++) {
                float x = acc[i][j][r];
                float th = fast_tanh(x);
                s[0] += th * as[j];
                s[1] += th * ad[j];
                #pragma unroll
                for (int jj = 0; jj < 5; jj++) s[2 + jj] += x * wfc[j][jj];
            }
            #pragma unroll
            for (int off = 1; off < 16; off <<= 1)
                #pragma unroll
                for (int q = 0; q < 7; q++) s[q] += __shfl_xor(s[q], off);
            if (lr == 0) {
                int m = m0 + i * 16 + lq * 4 + r;
                float* dst = base + (size_t)m * 8;
                #pragma unroll
                for (int q = 0; q < 7; q++) dst[q] = s[q];
            }
        }
    }
}

// ---- combine slices -> negss / E / Ep tables + interleaved T {sd,F,Fp,g0..g4} ----
__global__ __launch_bounds__(256) void k_comb_hp2(
    const float* __restrict__ gpart,
    float* __restrict__ negss, float* __restrict__ Etab, float* __restrict__ Eptab,
    float* __restrict__ T)
{
    int idx = blockIdx.x * 256 + threadIdx.x;   // h*NT + m
    float s[7] = {0,0,0,0,0,0,0};
    #pragma unroll
    for (int sl = 0; sl < 4; sl++) {
        const float* p = gpart + (((size_t)(idx >> 12) * 4 + sl) * NT + (idx & (NT - 1))) * 8;
        #pragma unroll
        for (int q = 0; q < 7; q++) s[q] += p[q];
    }
    negss[idx] = -s[0];
    Etab[idx]  = __expf(s[0]);
    Eptab[idx] = __expf(NEG * s[0]);
    float4 t0 = {s[1], __expf(s[1]), __expf(NEG * s[1]), s[2]};
    float4 t1 = {s[3], s[4], s[5], s[6]};
    *(float4*)(T + (size_t)idx * 8)     = t0;
    *(float4*)(T + (size_t)idx * 8 + 4) = t1;
}

// ---- c[j] = b2 . W_fc[:,j] ----
__global__ void k_cvec(const float* __restrict__ b2, const float* __restrict__ W_fc,
                       float* __restrict__ c) {
    int t = threadIdx.x;
    float v[5];
    #pragma unroll
    for (int j = 0; j < 5; j++) v[j] = b2[t] * W_fc[t * 5 + j];
    #pragma unroll
    for (int off = 1; off < 64; off <<= 1)
        #pragma unroll
        for (int j = 0; j < 5; j++) v[j] += __shfl_xor(v[j], off);
    __shared__ float red[4][5];
    int w = t >> 6, l = t & 63;
    if (l == 0) { for (int j = 0; j < 5; j++) red[w][j] = v[j]; }
    __syncthreads();
    if (t == 0)
        for (int j = 0; j < 5; j++) c[j] = red[0][j] + red[1][j] + red[2][j] + red[3][j];
}

// ---- GAT2 attention: exp-free, one head/block, 64 rows/block (8/wave), LDS adj ----
// grid: nb(56) x h(8) x c(2); part[((c*3584+n)*8+h)*6 + {den,num0..4}]
__global__ __launch_bounds__(512) void k_gat2_attn(
    const u64* __restrict__ packed, const float* __restrict__ negss,
    const float* __restrict__ Etab, const float* __restrict__ Eptab,
    const float* __restrict__ T, float* __restrict__ part)
{
    __shared__ u64 pw[64 * 32];   // 16 KB: [row][qword]
    int t = threadIdx.x;
    int w = t >> 6, l = t & 63;
    int b = blockIdx.x;
    int nb = b % 56;
    int h  = (b / 56) & 7;
    int c  = b / 448;             // 0..1 : m in [c*2048, c*2048+2048)
    int rbase = nb * 64;
    #pragma unroll
    for (int u = 0; u < 4; u++) {
        int idx = u * 512 + t;    // 2048 words
        int row = idx >> 5, q = idx & 31;
        pw[idx] = packed[(size_t)(rbase + row) * 64 + c * 32 + q];
    }
    __syncthreads();
    int n0 = rbase + w * 8;       // this wave's 8 query rows
    float ns[8], E[8], Ep[8];
    #pragma unroll
    for (int i = 0; i < 8; i++) {
        int r = h * NT + n0 + i;
        ns[i] = rfl(negss[r]);
        E[i]  = rfl(Etab[r]);
        Ep[i] = rfl(Eptab[r]);
    }
    float den[8] = {0,0,0,0,0,0,0,0};
    float num[8][5] = {{0}};
    const float* Th = T + ((size_t)h * NT + c * 2048) * 8;
    for (int q = 0; q < 32; q++) {
        const float* tp = Th + (size_t)(q * 64 + l) * 8;
        float4 t0 = *(const float4*)tp;
        float4 t1 = *(const float4*)(tp + 4);
        float sd = t0.x, F = t0.y, Fp = t0.z;
        float g0 = t0.w, g1 = t1.x, g2 = t1.y, g3 = t1.z, g4 = t1.w;
        #pragma unroll
        for (int i = 0; i < 8; i++) {
            u64 word = pw[(w * 8 + i) * 32 + q];   // broadcast ds_read_b64
            float pa = F * E[i];
            float pb = Fp * Ep[i];
            float pp0 = (sd >= ns[i]) ? pa : pb;
            float pp = ((word >> l) & 1ull) ? pp0 : 0.0f;
            den[i] += pp;
            num[i][0] = fmaf(pp, g0, num[i][0]);
            num[i][1] = fmaf(pp, g1, num[i][1]);
            num[i][2] = fmaf(pp, g2, num[i][2]);
            num[i][3] = fmaf(pp, g3, num[i][3]);
            num[i][4] = fmaf(pp, g4, num[i][4]);
        }
    }
    #pragma unroll
    for (int i = 0; i < 8; i++) {
        float v[6];
        v[0] = den[i];
        #pragma unroll
        for (int j = 0; j < 5; j++) v[1 + j] = num[i][j];
        #pragma unroll
        for (int off = 1; off < 64; off <<= 1)
            #pragma unroll
            for (int k = 0; k < 6; k++) v[k] += __shfl_xor(v[k], off);
        if (l == 0) {
            float* dst = part + (((size_t)c * NW + n0 + i) * 8 + h) * 6;
            #pragma unroll
            for (int k = 0; k < 6; k++) dst[k] = v[k];
        }
    }
}

// ---- combine chunks + heads -> hf[n][5] ----
__global__ __launch_bounds__(256) void k_gat2_comb(const float* __restrict__ part,
                                                   float* __restrict__ hf) {
    int idx = blockIdx.x * 256 + threadIdx.x;  // n*8 + h
    int n = idx >> 3, h = idx & 7;
    float den = 0, num[5] = {0,0,0,0,0};
    #pragma unroll
    for (int cc = 0; cc < 2; cc++) {
        const float* p = part + (((size_t)cc * NW + n) * 8 + h) * 6;
        den += p[0];
        #pragma unroll
        for (int j = 0; j < 5; j++) num[j] += p[1 + j];
    }
    float inv = 1.0f / (den * 8.0f);
    float v[5];
    #pragma unroll
    for (int j = 0; j < 5; j++) v[j] = num[j] * inv;
    #pragma unroll
    for (int off = 1; off < 8; off <<= 1)
        #pragma unroll
        for (int j = 0; j < 5; j++) v[j] += __shfl_xor(v[j], off);
    if (h == 0) {
        #pragma unroll
        for (int j = 0; j < 5; j++) hf[n * 5 + j] = v[j];
    }
}

// ---- out[b][j] = (input[b].hf[:,j]) / sum(input[b]) + c[j] + b_fc[j] ----
__global__ __launch_bounds__(256) void k_final(
    const float* __restrict__ input, const float* __restrict__ hf,
    const float* __restrict__ cvec, const float* __restrict__ b_fc,
    float* __restrict__ out)
{
    int b = blockIdx.x, t = threadIdx.x;
    const float4* row4 = (const float4*)(input + (size_t)b * NW);
    const float4* hf4 = (const float4*)hf;
    float s = 0.f, a[5] = {0.f, 0.f, 0.f, 0.f, 0.f};
    for (int idx = t; idx < NW / 4; idx += 256) {
        float4 x = row4[idx];
        float f[20];
        #pragma unroll
        for (int q = 0; q < 5; q++) *(float4*)(f + 4 * q) = hf4[idx * 5 + q];
        s += x.x + x.y + x.z + x.w;
        #pragma unroll
        for (int j = 0; j < 5; j++)
            a[j] += x.x * f[j] + x.y * f[5 + j] + x.z * f[10 + j] + x.w * f[15 + j];
    }
    #pragma unroll
    for (int off = 1; off < 64; off <<= 1) {
        s += __shfl_xor(s, off);
        #pragma unroll
        for (int j = 0; j < 5; j++) a[j] += __shfl_xor(a[j], off);
    }
    __shared__ float red[4][6];
    int w = t >> 6, l = t & 63;
    if (l == 0) { red[w][0] = s; for (int j = 0; j < 5; j++) red[w][j + 1] = a[j]; }
    __syncthreads();
    if (t < 5) {
        float st = red[0][0] + red[1][0] + red[2][0] + red[3][0];
        float aj = red[0][t + 1] + red[1][t + 1] + red[2][t + 1] + red[3][t + 1];
        out[b * 5 + t] = aj / st + cvec[t] + b_fc[t];
    }
}

extern "C" void kernel_launch(void* const* d_in, const int* in_sizes, int n_in,
                              void* d_out, int out_size, void* d_ws, size_t ws_size,
                              hipStream_t stream) {
    const float* input   = (const float*)d_in[0];
    const float* pf      = (const float*)d_in[1];
    const float* wf      = (const float*)d_in[2];
    const float* w1      = (const float*)d_in[3];
    const float* a_src1  = (const float*)d_in[4];
    const float* a_dst1  = (const float*)d_in[5];
    const float* b1      = (const float*)d_in[6];
    const float* w2      = (const float*)d_in[7];
    const float* a_src2  = (const float*)d_in[8];
    const float* a_dst2  = (const float*)d_in[9];
    const float* b2      = (const float*)d_in[10];
    const float* W_fc    = (const float*)d_in[11];
    const float* b_fc    = (const float*)d_in[12];
    const int* pern_adj  = (const int*)d_in[13];
    const int* wp_adj    = (const int*)d_in[14];
    float* out = (float*)d_out;

    char* ws = (char*)d_ws;
    unsigned short* abf    = (unsigned short*)(ws);            // 2 MB
    unsigned short* btbf   = (unsigned short*)(ws + 2097152);  // 1 MB
    float*          hp1    = (float*)(ws + 3145728);           // 512 KB
    float*          ss1    = (float*)(ws + 3670016);           // 16 KB
    float*          sd1    = (float*)(ws + 3686400);           // 16 KB
    float*          negss  = (float*)(ws + 3702784);           // 128 KB
    float*          Etab   = (float*)(ws + 3833856);           // 128 KB
    float*          Eptab  = (float*)(ws + 3964928);           // 128 KB
    float*          T      = (float*)(ws + 4096000);           // 1 MB
    float*          hf     = (float*)(ws + 5144576);           // 70 KB
    float*          cvec   = (float*)(ws + 5216256);           // 64 B
    u64*            packed = (u64*)(ws + 5216512);             // 1.75 MB
    float*          gpart  = (float*)(ws + 7051520);           // 4 MB
    float*          part   = (float*)(ws + 11245824);          // 1.4 MB

    k_conv_word<<<3584, 256, 0, stream>>>(wf, abf);
    k_gat1_hp<<<64, 256, 0, stream>>>(pf, w1, a_src1, a_dst1, hp1, ss1, sd1);
    k_gat1_attn<<<256, 256, 0, stream>>>(pern_adj, hp1, ss1, sd1, b1, abf);
    k_conv_w2<<<2048, 256, 0, stream>>>(w2, btbf);
    k_pack_adj<<<896, 256, 0, stream>>>(wp_adj, packed);
    k_gemm_hp2<<<512, 256, 0, stream>>>(abf, btbf, a_src2, a_dst2, W_fc, gpart);
    k_comb_hp2<<<128, 256, 0, stream>>>(gpart, negss, Etab, Eptab, T);
    k_cvec<<<1, 256, 0, stream>>>(b2, W_fc, cvec);
    k_gat2_attn<<<896, 512, 0, stream>>>(packed, negss, Etab, Eptab, T, part);
    k_gat2_comb<<<112, 256, 0, stream>>>(part, hf);
    k_final<<<1024, 256, 0, stream>>>(input, hf, cvec, b_fc, out);
}